// Round 8
// baseline (265.067 us; speedup 1.0000x reference)
//
#include <hip/hip_runtime.h>

typedef __attribute__((ext_vector_type(8))) short bf16x8;
typedef __attribute__((ext_vector_type(4))) float f32x4;

__device__ __forceinline__ unsigned short f2bf(float f) {
    union { float f; unsigned int u; } v; v.f = f;
    unsigned int u = v.u;
    return (unsigned short)((u + 0x7FFFu + ((u >> 16) & 1u)) >> 16);
}

__device__ __forceinline__ void cp16_g2l(const void* g, void* l) {
    __builtin_amdgcn_global_load_lds(
        (const __attribute__((address_space(1))) unsigned int*)g,
        (__attribute__((address_space(3))) unsigned int*)l, 16, 0, 0);
}

// Single-kernel whole-tree evaluation.
// 512 blocks; block b owns rows [b*R_j, (b+1)*R_j) at every level j (R_j = 2<<j).
// Children of that range are exactly the block's own range at level j+1
// -> zero inter-block dependencies; levels separated by intra-block drains.
// emb image layout (global-row keyed): row Rg, col n ->
//   elem = (Rg>>7)*16384 + (Rg&1)*8192 + ((Rg&127)>>1)*128 + (n ^ ((((Rg&127)>>1)&7)<<3))
// Full 64-row tiles (child base 128-aligned): linear 32KiB global_load_lds DMA.
// Partial tiles (R<64): reg-staged copy — per-lane source with GLOBAL-il swizzle,
// ds_write dest with LOCAL-il swizzle (fixes ilBase&7!=0 at j<=1 and the
// wave-straddle dest-divergence at j=0 that broke round 7).
__global__ __launch_bounds__(256, 2) void k_tree(
    const float* __restrict__ c0, const float* __restrict__ c1,
    const float* __restrict__ c2, const float* __restrict__ c3,
    const float* __restrict__ c4, const float* __restrict__ c5,
    const float* __restrict__ c6, const float* __restrict__ c7,
    const float* __restrict__ c8, const float* __restrict__ c9,
    const float* __restrict__ Wu, const float* __restrict__ bu,
    const float* __restrict__ Wh, const float* __restrict__ bh,
    unsigned short* __restrict__ bufE, unsigned short* __restrict__ bufO,
    float* __restrict__ outF)
{
    // LDS: 32K (A) + 16K (u) + 4K (wu) = 52 KiB
    __shared__ __align__(16) unsigned short A_lds[2][64][128]; // [cc][il][n^swz]
    __shared__ __align__(16) unsigned short u_lds[64][128];    // [i][n^swz]
    __shared__ __align__(16) unsigned short wu_lds[8][32][8];  // [nf][l4*16+l15][e]

    const int tid = threadIdx.x, lane = tid & 63, wid = tid >> 6;
    const int l15 = lane & 15, l4 = lane >> 4;

    // ---- persistent W fragments (pinned vs rematerialization) ----
    bf16x8 wreg[2][12];
    #pragma unroll
    for (int nf2 = 0; nf2 < 2; ++nf2) {
        int n = wid * 32 + nf2 * 16 + l15;
        #pragma unroll
        for (int kb = 0; kb < 12; ++kb) {
            const float* wp = Wh + n * 384 + kb * 32 + l4 * 8;
            f32x4 lo = *(const f32x4*)wp;
            f32x4 hi = *(const f32x4*)(wp + 4);
            bf16x8 v;
            #pragma unroll
            for (int e = 0; e < 4; ++e) {
                ((unsigned short*)&v)[e]     = f2bf(lo[e]);
                ((unsigned short*)&v)[e + 4] = f2bf(hi[e]);
            }
            wreg[nf2][kb] = v;
        }
    }
    #pragma unroll
    for (int kb = 0; kb < 12; ++kb)
        asm volatile("" : "+v"(wreg[0][kb]), "+v"(wreg[1][kb]));

    // ---- Wu/bu fragment table in LDS (wave 0 writes) ----
    if (wid == 0 && l4 < 2) {
        #pragma unroll
        for (int nf = 0; nf < 8; ++nf) {
            int n = nf * 16 + l15;
            bf16x8 v = {0, 0, 0, 0, 0, 0, 0, 0};
            if (l4 == 0) {
                #pragma unroll
                for (int k = 0; k < 8; ++k) ((unsigned short*)&v)[k] = f2bf(Wu[n * 8 + k]);
            } else {
                ((unsigned short*)&v)[0] = f2bf(bu[n]);   // bias column (k=8)
            }
            *(bf16x8*)&wu_lds[nf][l4 * 16 + l15][0] = v;
        }
    }
    const float bhv0 = bh[wid * 32 + l15];
    const float bhv1 = bh[wid * 32 + 16 + l15];

    bf16x8 zeroA = {0, 0, 0, 0, 0, 0, 0, 0};
    bf16x8 onesA = zeroA; ((unsigned short*)&onesA)[0] = 0x3F80;  // 1.0 at k=8

    __syncthreads();  // wu_lds visible

    f32x4 cO0 = {0,0,0,0}, cO1 = {0,0,0,0};
    f32x4 cC00 = {0,0,0,0}, cC01 = {0,0,0,0}, cC10 = {0,0,0,0}, cC11 = {0,0,0,0};

    for (int j = 8; j >= 0; --j) {
        const bool LEAF = (j == 8), LAST = (j == 0);
        const int R = 2 << j;                       // rows/block at this level
        const int T = (R >= 64) ? (R >> 6) : 1;     // tiles/block
        const int M = (R < 64) ? R : 64;            // valid rows in (only) tile
        const float* contO;
        switch (j) {
            case 8: contO = c8; break;  case 7: contO = c7; break;
            case 6: contO = c6; break;  case 5: contO = c5; break;
            case 4: contO = c4; break;  case 3: contO = c3; break;
            case 2: contO = c2; break;  case 1: contO = c1; break;
            default: contO = c0; break;
        }
        const unsigned short* eIn  = (j & 1) ? bufE : bufO;
        unsigned short*       eOut = (j & 1) ? bufO : bufE;
        const size_t rowBase  = (size_t)blockIdx.x * (size_t)R;
        const size_t crowBase = rowBase * 2;

        // ---- level prologue: tile-0 inputs ----
        if (!LEAF) {
            if (M == 64) {  // full tile: contiguous 32 KiB linear DMA
                const unsigned short* gb = eIn + (crowBase >> 7) * 16384;
                #pragma unroll
                for (int it = 0; it < 8; ++it) {
                    int q = tid + it * 256;
                    cp16_g2l(gb + (size_t)q * 8, &A_lds[0][0][0] + q * 8);
                }
            } else {
                // partial: reg-staged, swizzle-correct (global-il source, local-il dest)
                const int ilBase = ((int)(crowBase & 127)) >> 1;
                const unsigned short* gb = eIn + (crowBase >> 7) * 16384 + (size_t)ilBase * 128;
                const int per = 16 * M, tot = 32 * M;
                for (int q = tid; q < tot; q += 256) {
                    int cc = (q >= per) ? 1 : 0;
                    int qq = q - (cc ? per : 0);
                    int il_loc = qq >> 4, slot = qq & 15;
                    int il_g = ilBase + il_loc;
                    int kc = slot ^ (il_loc & 7);        // logical k-chunk stored at this dest slot
                    int src_slot = kc ^ (il_g & 7);      // where the producer put it
                    bf16x8 v = *(const bf16x8*)(gb + cc * 8192 + il_loc * 128 + src_slot * 8);
                    *(bf16x8*)(&A_lds[cc][il_loc][slot * 8]) = v;
                }
            }
            __builtin_amdgcn_sched_barrier(0);  // pin: staging issued before contents loads
        }
        if (l4 == 0) {
            size_t row = rowBase + (size_t)(wid * 16 + l15);
            size_t mx = rowBase + R - 1; if (row > mx) row = mx;
            const float* p = contO + row * 8;
            cO0 = *(const f32x4*)p; cO1 = *(const f32x4*)(p + 4);
            if (LEAF) {
                const float* pc = c9 + (crowBase + (size_t)(wid * 32 + l15)) * 8;
                cC00 = *(const f32x4*)pc;         cC01 = *(const f32x4*)(pc + 4);
                cC10 = *(const f32x4*)(pc + 128); cC11 = *(const f32x4*)(pc + 132);
            }
        }

        for (int tt = 0; tt < T; ++tt) {
            // ======== u-phase (own rows) ========
            {
                bf16x8 au = zeroA;
                if (l4 == 0) {
                    #pragma unroll
                    for (int e = 0; e < 4; ++e) {
                        ((unsigned short*)&au)[e]     = f2bf(cO0[e]);
                        ((unsigned short*)&au)[e + 4] = f2bf(cO1[e]);
                    }
                } else if (l4 == 1) au = onesA;
                #pragma unroll
                for (int nf = 0; nf < 8; ++nf) {
                    bf16x8 wv = zeroA;
                    if (l4 < 2) wv = *(const bf16x8*)&wu_lds[nf][l4 * 16 + l15][0];
                    f32x4 z = {0.f, 0.f, 0.f, 0.f};
                    z = __builtin_amdgcn_mfma_f32_16x16x32_bf16(au, wv, z, 0, 0, 0);
                    #pragma unroll
                    for (int r = 0; r < 4; ++r) {
                        int iu = wid * 16 + l4 * 4 + r;
                        int n = nf * 16 + l15;
                        u_lds[iu][n ^ ((iu & 7) << 3)] = f2bf(fmaxf(z[r], 0.f));
                    }
                }
            }
            if (LEAF) {  // child-u directly into A image
                #pragma unroll
                for (int rb = 0; rb < 2; ++rb) {
                    bf16x8 ac = zeroA;
                    if (l4 == 0) {
                        f32x4 a = rb ? cC10 : cC00, b2 = rb ? cC11 : cC01;
                        #pragma unroll
                        for (int e = 0; e < 4; ++e) {
                            ((unsigned short*)&ac)[e]     = f2bf(a[e]);
                            ((unsigned short*)&ac)[e + 4] = f2bf(b2[e]);
                        }
                    } else if (l4 == 1) ac = onesA;
                    #pragma unroll
                    for (int nf = 0; nf < 8; ++nf) {
                        bf16x8 wv = zeroA;
                        if (l4 < 2) wv = *(const bf16x8*)&wu_lds[nf][l4 * 16 + l15][0];
                        f32x4 z = {0.f, 0.f, 0.f, 0.f};
                        z = __builtin_amdgcn_mfma_f32_16x16x32_bf16(ac, wv, z, 0, 0, 0);
                        #pragma unroll
                        for (int r = 0; r < 4; ++r) {
                            int rr = wid * 32 + rb * 16 + l4 * 4 + r;
                            int cc = rr & 1, il = rr >> 1;
                            int n = nf * 16 + l15;
                            A_lds[cc][il][n ^ ((il & 7) << 3)] = f2bf(fmaxf(z[r], 0.f));
                        }
                    }
                }
            }
            // ---- prefetch next tile's contents (clamped; uniform VMEM counts) ----
            {
                int tn = (tt + 1 < T) ? tt + 1 : tt;
                if (l4 == 0) {
                    size_t row = rowBase + (size_t)tn * 64 + (size_t)(wid * 16 + l15);
                    size_t mx = rowBase + R - 1; if (row > mx) row = mx;
                    const float* p = contO + row * 8;
                    cO0 = *(const f32x4*)p; cO1 = *(const f32x4*)(p + 4);
                    if (LEAF) {
                        const float* pc = c9 + (crowBase + (size_t)tn * 128 + (size_t)(wid * 32 + l15)) * 8;
                        cC00 = *(const f32x4*)pc;         cC01 = *(const f32x4*)(pc + 4);
                        cC10 = *(const f32x4*)(pc + 128); cC11 = *(const f32x4*)(pc + 132);
                    }
                }
            }

            // ======== phase barrier: A ready (counted vmcnt), u visible ========
            if (!LEAF) {
                if (tt == 0) asm volatile("s_waitcnt vmcnt(2)" ::: "memory");   // drain prologue staging; leave contents prefetch
                else         asm volatile("s_waitcnt vmcnt(34)" ::: "memory");  // drain 8 DMA; leave 32 stores + 2 prefetch
            }
            asm volatile("s_waitcnt lgkmcnt(0)" ::: "memory");
            __builtin_amdgcn_sched_barrier(0);
            __builtin_amdgcn_s_barrier();
            __builtin_amdgcn_sched_barrier(0);

            // ======== main GEMM: K=384 = [child0 | child1 | u] ========
            f32x4 acc[4][2];
            #pragma unroll
            for (int mf = 0; mf < 4; ++mf) {
                acc[mf][0] = (f32x4){bhv0, bhv0, bhv0, bhv0};
                acc[mf][1] = (f32x4){bhv1, bhv1, bhv1, bhv1};
            }
            __builtin_amdgcn_s_setprio(1);
            #pragma unroll
            for (int kb = 0; kb < 8; ++kb) {
                bf16x8 af[4];
                #pragma unroll
                for (int mf = 0; mf < 4; ++mf) {
                    int i = mf * 16 + l15;
                    af[mf] = *(const bf16x8*)&A_lds[kb >> 2][i][((((kb & 3) * 4) + l4) ^ (i & 7)) * 8];
                }
                #pragma unroll
                for (int mf = 0; mf < 4; ++mf) {
                    acc[mf][0] = __builtin_amdgcn_mfma_f32_16x16x32_bf16(af[mf], wreg[0][kb], acc[mf][0], 0, 0, 0);
                    acc[mf][1] = __builtin_amdgcn_mfma_f32_16x16x32_bf16(af[mf], wreg[1][kb], acc[mf][1], 0, 0, 0);
                }
            }
            __builtin_amdgcn_s_setprio(0);

            // A consumed -> barrier, then prefetch next tile's A DMA (full tiles only)
            if (!LEAF) {
                asm volatile("s_waitcnt lgkmcnt(0)" ::: "memory");
                __builtin_amdgcn_sched_barrier(0);
                __builtin_amdgcn_s_barrier();
                __builtin_amdgcn_sched_barrier(0);
                if (tt + 1 < T) {
                    const unsigned short* gb = eIn + ((crowBase + (size_t)(tt + 1) * 128) >> 7) * 16384;
                    #pragma unroll
                    for (int it = 0; it < 8; ++it) {
                        int q = tid + it * 256;
                        cp16_g2l(gb + (size_t)q * 8, &A_lds[0][0][0] + q * 8);
                    }
                    __builtin_amdgcn_sched_barrier(0);
                }
            }

            __builtin_amdgcn_s_setprio(1);
            #pragma unroll
            for (int kb = 8; kb < 12; ++kb) {
                bf16x8 af[4];
                #pragma unroll
                for (int mf = 0; mf < 4; ++mf) {
                    int i = mf * 16 + l15;
                    af[mf] = *(const bf16x8*)&u_lds[i][((((kb - 8) * 4) + l4) ^ (i & 7)) * 8];
                }
                #pragma unroll
                for (int mf = 0; mf < 4; ++mf) {
                    acc[mf][0] = __builtin_amdgcn_mfma_f32_16x16x32_bf16(af[mf], wreg[0][kb], acc[mf][0], 0, 0, 0);
                    acc[mf][1] = __builtin_amdgcn_mfma_f32_16x16x32_bf16(af[mf], wreg[1][kb], acc[mf][1], 0, 0, 0);
                }
            }
            __builtin_amdgcn_s_setprio(0);

            // ======== epilogue: direct stores ========
            if (LAST) {
                #pragma unroll
                for (int mf = 0; mf < 4; ++mf)
                    #pragma unroll
                    for (int nf2 = 0; nf2 < 2; ++nf2)
                        #pragma unroll
                        for (int r = 0; r < 4; ++r) {
                            int i = mf * 16 + l4 * 4 + r;
                            if (i < M) {
                                int n = wid * 32 + nf2 * 16 + l15;
                                outF[(rowBase + i) * 128 + n] = fmaxf(acc[mf][nf2][r], 0.f);
                            }
                        }
            } else if (M == 64) {  // full tile: unmasked image stores
                size_t rowLoc = rowBase + (size_t)tt * 64;
                #pragma unroll
                for (int mf = 0; mf < 4; ++mf)
                    #pragma unroll
                    for (int nf2 = 0; nf2 < 2; ++nf2)
                        #pragma unroll
                        for (int r = 0; r < 4; ++r) {
                            int i = mf * 16 + l4 * 4 + r;
                            size_t Rg = rowLoc + i;
                            int n = wid * 32 + nf2 * 16 + l15;
                            int rr = (int)(Rg & 127);
                            size_t e = (Rg >> 7) * 16384 + (size_t)((rr & 1) * 8192)
                                     + (size_t)((rr >> 1) * 128)
                                     + (size_t)(n ^ (((rr >> 1) & 7) << 3));
                            eOut[e] = f2bf(fmaxf(acc[mf][nf2][r], 0.f));
                        }
            } else {               // partial tile: masked
                #pragma unroll
                for (int mf = 0; mf < 4; ++mf)
                    #pragma unroll
                    for (int nf2 = 0; nf2 < 2; ++nf2)
                        #pragma unroll
                        for (int r = 0; r < 4; ++r) {
                            int i = mf * 16 + l4 * 4 + r;
                            if (i < M) {
                                size_t Rg = rowBase + i;
                                int n = wid * 32 + nf2 * 16 + l15;
                                int rr = (int)(Rg & 127);
                                size_t e = (Rg >> 7) * 16384 + (size_t)((rr & 1) * 8192)
                                         + (size_t)((rr >> 1) * 128)
                                         + (size_t)(n ^ (((rr >> 1) & 7) << 3));
                                eOut[e] = f2bf(fmaxf(acc[mf][nf2][r], 0.f));
                            }
                        }
            }

            // ======== post barrier: u_lds/A_lds free for next tile's writes ========
            asm volatile("s_waitcnt lgkmcnt(0)" ::: "memory");
            __builtin_amdgcn_sched_barrier(0);
            __builtin_amdgcn_s_barrier();
        }

        // ---- level end: image stores visible before next level's staging reads ----
        asm volatile("s_waitcnt vmcnt(0) lgkmcnt(0)" ::: "memory");
        __builtin_amdgcn_sched_barrier(0);
        __builtin_amdgcn_s_barrier();
    }
}

extern "C" void kernel_launch(void* const* d_in, const int* in_sizes, int n_in,
                              void* d_out, int out_size, void* d_ws, size_t ws_size,
                              hipStream_t stream) {
    const float* c[10];
    for (int j = 0; j < 10; ++j) c[j] = (const float*)d_in[j];
    const float* Wu = (const float*)d_in[19];
    const float* bu = (const float*)d_in[20];
    const float* Wh = (const float*)d_in[21];
    const float* bh = (const float*)d_in[22];

    unsigned short* bufE = (unsigned short*)d_ws;                        // 64 MiB (even-level embs)
    unsigned short* bufO = (unsigned short*)((char*)d_ws + (64u << 20)); // 32 MiB (odd-level embs)

    k_tree<<<512, 256, 0, stream>>>(c[0], c[1], c[2], c[3], c[4], c[5], c[6], c[7], c[8], c[9],
                                    Wu, bu, Wh, bh, bufE, bufO, (float*)d_out);
}